// Round 5
// baseline (317.759 us; speedup 1.0000x reference)
//
#include <hip/hip_runtime.h>
#include <hip/hip_bf16.h>
#include <cstddef>

#define NN 8192
#define FF 128
#define EPSF 1e-8f
#define KSPLIT 8   // grid-level split-K for spmm

typedef __attribute__((ext_vector_type(8))) short short8_t;
typedef __attribute__((ext_vector_type(4))) float f32x4_t;

static __device__ __forceinline__ unsigned short f2bf(float f) {
    unsigned u = __builtin_bit_cast(unsigned, f);
    u = (u + 0x7FFFu + ((u >> 16) & 1u)) >> 16;   // round-to-nearest-even
    return (unsigned short)u;
}
static __device__ __forceinline__ float bf2f(unsigned short h) {
    return __builtin_bit_cast(float, ((unsigned)h) << 16);
}

// ---------------------------------------------------------------------------
// Pass A1: L = adj + learn (eps*noise <= 1e-8: below bf16 ulp of L and
// ~5e-9 relative on degree -> noise never read; proven R3).
// ONE-SHOT per thread: no loop -> compiler cannot serialize the loads.
// Block = 2048 contiguous elems of one row (4 blocks/row); partial row-sum
// via one atomicAdd per block into degree[] (zeroed beforehand).
// ---------------------------------------------------------------------------
#define CCHUNK 2048
__global__ __launch_bounds__(256) void fuse_combine_kernel(
    const float* __restrict__ adj, const float* __restrict__ learn,
    unsigned short* __restrict__ Lb, float* __restrict__ degree)
{
    const int row = blockIdx.x >> 2;
    const size_t base = (size_t)row * NN + (blockIdx.x & 3) * CCHUNK
                      + (size_t)threadIdx.x * 8;
    const f32x4_t a0 = *(const f32x4_t*)(adj   + base);
    const f32x4_t a1 = *(const f32x4_t*)(adj   + base + 4);
    const f32x4_t l0 = *(const f32x4_t*)(learn + base);
    const f32x4_t l1 = *(const f32x4_t*)(learn + base + 4);
    const f32x4_t v0 = a0 + l0;
    const f32x4_t v1 = a1 + l1;
    short8_t pk;
    pk[0] = (short)f2bf(v0.x); pk[1] = (short)f2bf(v0.y);
    pk[2] = (short)f2bf(v0.z); pk[3] = (short)f2bf(v0.w);
    pk[4] = (short)f2bf(v1.x); pk[5] = (short)f2bf(v1.y);
    pk[6] = (short)f2bf(v1.z); pk[7] = (short)f2bf(v1.w);
    *(short8_t*)(Lb + base) = pk;

    float acc = (v0.x + v0.y) + (v0.z + v0.w)
              + (v1.x + v1.y) + (v1.z + v1.w);
#pragma unroll
    for (int o = 32; o; o >>= 1) acc += __shfl_down(acc, o);
    __shared__ float red[4];
    if ((threadIdx.x & 63) == 0) red[threadIdx.x >> 6] = acc;
    __syncthreads();
    if (threadIdx.x == 0)
        atomicAdd(degree + row, red[0] + red[1] + red[2] + red[3]);
}

// s[i] = rsqrt(degree[i] + 1 (self loop) + eps)
__global__ __launch_bounds__(256) void s_kernel(
    const float* __restrict__ degree, float* __restrict__ s)
{
    const int i = blockIdx.x * 256 + threadIdx.x;
    s[i] = rsqrtf(degree[i] + 1.0f + EPSF);
}

// ---------------------------------------------------------------------------
// Pass B: ss_t[n][j] = s[j] * (x @ W)[j][n]  (bf16, 2 MB, L2/L3-resident)
// ---------------------------------------------------------------------------
__global__ __launch_bounds__(256) void support_kernel(
    const float* __restrict__ x, const float* __restrict__ w,
    const float* __restrict__ s, unsigned short* __restrict__ ss_t)
{
    __shared__ float Ws[128 * 128];    // 64 KB
    __shared__ float Xs[32][128];      // 16 KB
    for (int i = threadIdx.x; i < 128 * 128 / 4; i += 256)
        ((float4*)Ws)[i] = ((const float4*)w)[i];
    const int rbase = blockIdx.x * 32;
    for (int i = threadIdx.x; i < 32 * 128 / 4; i += 256)
        ((float4*)&Xs[0][0])[i] = ((const float4*)(x + (size_t)rbase * 128))[i];
    __syncthreads();

    const int c = threadIdx.x & 127;
    const int h = threadIdx.x >> 7;
    for (int r = h; r < 32; r += 2) {
        float acc = 0.f;
#pragma unroll 8
        for (int k = 0; k < 128; ++k) acc += Xs[r][k] * Ws[k * 128 + c];
        const int grow = rbase + r;
        ss_t[(size_t)c * NN + grow] = f2bf(acc * s[grow]);
    }
}

// ---------------------------------------------------------------------------
// Pass C: out[i][n] = s[i] * ( sum_j L[i][j]*SS[j][n] + SS[i][n] )
// 16 rows/wave, grid (128, KSPLIT=8) = 1024 blocks -> ~16 waves/CU;
// explicit 2-deep register prefetch (load k-step t+1 during MFMA of t).
// ATOMIC=false: split-K partials to ws (reduced by reduce_kernel).
// ---------------------------------------------------------------------------
template<bool ATOMIC>
__global__ __launch_bounds__(256) void spmm_bf16_kernel(
    const unsigned short* __restrict__ Lb,
    const unsigned short* __restrict__ ss_t,
    const float* __restrict__ s, float* __restrict__ outp)
{
    const int ks   = blockIdx.y;
    const int wave = threadIdx.x >> 6;
    const int lane = threadIdx.x & 63;
    const int m = lane & 15;            // A-row / B-col within fragment
    const int b = lane >> 4;            // k-subgroup (8 elems each)
    const int i0 = blockIdx.x * 64 + wave * 16;
    const size_t arow = (size_t)(i0 + m) * NN;
    const int kbeg = ks * (NN / KSPLIT);
    const int kend = kbeg + NN / KSPLIT;
    const unsigned short* bbase = ss_t + (size_t)m * NN;

    f32x4_t acc[8];
#pragma unroll
    for (int t = 0; t < 8; ++t) acc[t] = (f32x4_t){0.f, 0.f, 0.f, 0.f};

    // prologue: stage k-step 0
    int col = kbeg + 8 * b;
    short8_t aC = *(const short8_t*)(Lb + arow + col);
    short8_t bC[8];
#pragma unroll
    for (int nt = 0; nt < 8; ++nt)
        bC[nt] = *(const short8_t*)(bbase + (size_t)(nt * 16) * NN + col);

    for (int kk = kbeg; kk < kend - 32; kk += 32) {
        const int col2 = kk + 32 + 8 * b;
        const short8_t aN = *(const short8_t*)(Lb + arow + col2);
        short8_t bN[8];
#pragma unroll
        for (int nt = 0; nt < 8; ++nt)
            bN[nt] = *(const short8_t*)(bbase + (size_t)(nt * 16) * NN + col2);
#pragma unroll
        for (int nt = 0; nt < 8; ++nt)
            acc[nt] = __builtin_amdgcn_mfma_f32_16x16x32_bf16(aC, bC[nt],
                                                              acc[nt], 0, 0, 0);
        aC = aN;
#pragma unroll
        for (int nt = 0; nt < 8; ++nt) bC[nt] = bN[nt];
    }
#pragma unroll
    for (int nt = 0; nt < 8; ++nt)
        acc[nt] = __builtin_amdgcn_mfma_f32_16x16x32_bf16(aC, bC[nt],
                                                          acc[nt], 0, 0, 0);

    // C/D layout: col = lane&15, row = (lane>>4)*4 + reg  [measured m89/m91]
#pragma unroll
    for (int nt = 0; nt < 8; ++nt) {
        const int n = nt * 16 + m;
#pragma unroll
        for (int r = 0; r < 4; ++r) {
            const int ro = i0 + 4 * b + r;
            float v = acc[nt][r];
            if (ATOMIC) {
                if (ks == 0) v += bf2f(ss_t[(size_t)n * NN + ro]);
                atomicAdd(outp + (size_t)ro * FF + n, s[ro] * v);
            } else {
                outp[(size_t)ks * NN * FF + (size_t)ro * FF + n] = v;
            }
        }
    }
}

// Reduce KSPLIT partials + identity term + row scaling -> out (f32).
__global__ __launch_bounds__(256) void reduce_kernel(
    const float* __restrict__ part, const unsigned short* __restrict__ ss_t,
    const float* __restrict__ s, float* __restrict__ out)
{
    const int idx = blockIdx.x * 256 + threadIdx.x;   // 0 .. NN*FF-1
    const int gi = idx >> 7;          // row i
    const int cc = idx & 127;         // col n
    float v = 0.f;
#pragma unroll
    for (int k = 0; k < KSPLIT; ++k) v += part[(size_t)k * NN * FF + idx];
    v += bf2f(ss_t[(size_t)cc * NN + gi]);            // + I * SS
    out[idx] = s[gi] * v;
}

extern "C" void kernel_launch(void* const* d_in, const int* in_sizes, int n_in,
                              void* d_out, int out_size, void* d_ws, size_t ws_size,
                              hipStream_t stream) {
    const float* x     = (const float*)d_in[0];
    const float* adj   = (const float*)d_in[1];
    const float* w     = (const float*)d_in[3];
    const float* learn = (const float*)d_in[4];
    float* out = (float*)d_out;

    // ws layout: degree | s | ss_t | Lb | (part)
    float* degree = (float*)d_ws;
    float* s      = degree + NN;
    unsigned short* ss_t = (unsigned short*)(s + NN);
    unsigned short* Lb   = ss_t + (size_t)FF * NN;
    float* part          = (float*)(Lb + (size_t)NN * NN);

    const size_t need_base = 2 * NN * 4 + (size_t)FF * NN * 2
                           + (size_t)NN * NN * 2;
    const size_t need_part = need_base + (size_t)KSPLIT * NN * FF * 4; // ~162 MB

    hipMemsetAsync(degree, 0, NN * sizeof(float), stream);
    fuse_combine_kernel<<<NN * 4, 256, 0, stream>>>(adj, learn, Lb, degree);
    s_kernel<<<NN / 256, 256, 0, stream>>>(degree, s);
    support_kernel<<<NN / 32, 256, 0, stream>>>(x, w, s, ss_t);

    if (ws_size >= need_part) {
        spmm_bf16_kernel<false><<<dim3(NN / 64, KSPLIT), 256, 0, stream>>>(
            Lb, ss_t, s, part);
        reduce_kernel<<<NN * FF / 256, 256, 0, stream>>>(part, ss_t, s, out);
    } else {
        hipMemsetAsync(d_out, 0, (size_t)NN * FF * sizeof(float), stream);
        spmm_bf16_kernel<true><<<dim3(NN / 64, KSPLIT), 256, 0, stream>>>(
            Lb, ss_t, s, out);
    }
}

// Round 6
// 258.093 us; speedup vs baseline: 1.2312x; 1.2312x over previous
//
#include <hip/hip_runtime.h>
#include <hip/hip_bf16.h>
#include <cstddef>

#define NN 8192
#define FF 128
#define EPSF 1e-8f
#define KSPLIT 8   // grid-level split-K for spmm

typedef __attribute__((ext_vector_type(8))) short short8_t;
typedef __attribute__((ext_vector_type(4))) float f32x4_t;

static __device__ __forceinline__ unsigned short f2bf(float f) {
    unsigned u = __builtin_bit_cast(unsigned, f);
    u = (u + 0x7FFFu + ((u >> 16) & 1u)) >> 16;   // round-to-nearest-even
    return (unsigned short)u;
}
static __device__ __forceinline__ float bf2f(unsigned short h) {
    return __builtin_bit_cast(float, ((unsigned)h) << 16);
}

// ---------------------------------------------------------------------------
// Pass A1: L = adj + learn (eps*noise <= 1e-8: below bf16 ulp of L, ~5e-9
// relative on degree -> noise never read; proven R3).
// One-shot per thread, NONTEMPORAL loads for the 512 MB of single-use f32
// (no L3 allocation -> no thrash, keeps Lb L3-resident for the spmm).
// Each thread: 2 chunks x 16B per stream = 128 B in flight.
// Block = 4096 elems of one row (2 blocks/row); rowsum partial via one
// atomicAdd per block into degree[] (zeroed beforehand).
// ---------------------------------------------------------------------------
__global__ __launch_bounds__(256) void fuse_combine_kernel(
    const float* __restrict__ adj, const float* __restrict__ learn,
    unsigned short* __restrict__ Lb, float* __restrict__ degree)
{
    const int row = blockIdx.x >> 1;
    const size_t base = (size_t)row * NN + (blockIdx.x & 1) * 4096
                      + (size_t)threadIdx.x * 8;
    const f32x4_t a0 = __builtin_nontemporal_load((const f32x4_t*)(adj + base));
    const f32x4_t a1 = __builtin_nontemporal_load((const f32x4_t*)(adj + base + 4));
    const f32x4_t a2 = __builtin_nontemporal_load((const f32x4_t*)(adj + base + 2048));
    const f32x4_t a3 = __builtin_nontemporal_load((const f32x4_t*)(adj + base + 2052));
    const f32x4_t l0 = __builtin_nontemporal_load((const f32x4_t*)(learn + base));
    const f32x4_t l1 = __builtin_nontemporal_load((const f32x4_t*)(learn + base + 4));
    const f32x4_t l2 = __builtin_nontemporal_load((const f32x4_t*)(learn + base + 2048));
    const f32x4_t l3 = __builtin_nontemporal_load((const f32x4_t*)(learn + base + 2052));

    const f32x4_t v0 = a0 + l0, v1 = a1 + l1, v2 = a2 + l2, v3 = a3 + l3;
    short8_t p0, p1;
    p0[0] = (short)f2bf(v0.x); p0[1] = (short)f2bf(v0.y);
    p0[2] = (short)f2bf(v0.z); p0[3] = (short)f2bf(v0.w);
    p0[4] = (short)f2bf(v1.x); p0[5] = (short)f2bf(v1.y);
    p0[6] = (short)f2bf(v1.z); p0[7] = (short)f2bf(v1.w);
    p1[0] = (short)f2bf(v2.x); p1[1] = (short)f2bf(v2.y);
    p1[2] = (short)f2bf(v2.z); p1[3] = (short)f2bf(v2.w);
    p1[4] = (short)f2bf(v3.x); p1[5] = (short)f2bf(v3.y);
    p1[6] = (short)f2bf(v3.z); p1[7] = (short)f2bf(v3.w);
    *(short8_t*)(Lb + base) = p0;           // normal store: want Lb in L3
    *(short8_t*)(Lb + base + 2048) = p1;

    float acc = (v0.x + v0.y) + (v0.z + v0.w) + (v1.x + v1.y) + (v1.z + v1.w)
              + (v2.x + v2.y) + (v2.z + v2.w) + (v3.x + v3.y) + (v3.z + v3.w);
#pragma unroll
    for (int o = 32; o; o >>= 1) acc += __shfl_down(acc, o);
    __shared__ float red[4];
    if ((threadIdx.x & 63) == 0) red[threadIdx.x >> 6] = acc;
    __syncthreads();
    if (threadIdx.x == 0)
        atomicAdd(degree + row, red[0] + red[1] + red[2] + red[3]);
}

// s[i] = rsqrt(degree[i] + 1 (self loop) + eps)
__global__ __launch_bounds__(256) void s_kernel(
    const float* __restrict__ degree, float* __restrict__ s)
{
    const int i = blockIdx.x * 256 + threadIdx.x;
    s[i] = rsqrtf(degree[i] + 1.0f + EPSF);
}

// ---------------------------------------------------------------------------
// Pass B: ss_t[n][j] = s[j] * (x @ W)[j][n]  (bf16, 2 MB, L2/L3-resident)
// ---------------------------------------------------------------------------
__global__ __launch_bounds__(256) void support_kernel(
    const float* __restrict__ x, const float* __restrict__ w,
    const float* __restrict__ s, unsigned short* __restrict__ ss_t)
{
    __shared__ float Ws[128 * 128];    // 64 KB
    __shared__ float Xs[32][128];      // 16 KB
    for (int i = threadIdx.x; i < 128 * 128 / 4; i += 256)
        ((float4*)Ws)[i] = ((const float4*)w)[i];
    const int rbase = blockIdx.x * 32;
    for (int i = threadIdx.x; i < 32 * 128 / 4; i += 256)
        ((float4*)&Xs[0][0])[i] = ((const float4*)(x + (size_t)rbase * 128))[i];
    __syncthreads();

    const int c = threadIdx.x & 127;
    const int h = threadIdx.x >> 7;
    for (int r = h; r < 32; r += 2) {
        float acc = 0.f;
#pragma unroll 8
        for (int k = 0; k < 128; ++k) acc += Xs[r][k] * Ws[k * 128 + c];
        const int grow = rbase + r;
        ss_t[(size_t)c * NN + grow] = f2bf(acc * s[grow]);
    }
}

// ---------------------------------------------------------------------------
// Pass C (R4 exact, proven): out[i][n] = s[i]*(sum_j L[ij]*SS[j][n]+SS[i][n])
// Register-blocked: wave owns 32 rows (2 A-frags per B-frag), block = 128
// rows x 4 waves, KSPLIT=8 -> grid 512.
// ---------------------------------------------------------------------------
template<bool ATOMIC>
__global__ __launch_bounds__(256) void spmm_bf16_kernel(
    const unsigned short* __restrict__ Lb,
    const unsigned short* __restrict__ ss_t,
    const float* __restrict__ s, float* __restrict__ outp)
{
    const int ks   = blockIdx.y;            // 0..KSPLIT-1
    const int i0   = blockIdx.x * 128;      // M-block base
    const int wave = threadIdx.x >> 6;      // 0..3
    const int lane = threadIdx.x & 63;
    const int m = lane & 15;                // A-row / B-col within fragment
    const int b = lane >> 4;                // k-subgroup (8 elems each)
    const size_t a0off = (size_t)(i0 + wave * 32 + m) * NN;
    const size_t a1off = a0off + (size_t)16 * NN;
    const int kbeg = ks * (NN / KSPLIT);

    f32x4_t acc[2][8];
#pragma unroll
    for (int f = 0; f < 2; ++f)
#pragma unroll
        for (int t = 0; t < 8; ++t) acc[f][t] = (f32x4_t){0.f, 0.f, 0.f, 0.f};

    for (int kk = kbeg; kk < kbeg + NN / KSPLIT; kk += 32) {
        const int col = kk + 8 * b;
        const short8_t af0 = *(const short8_t*)(Lb + a0off + col);
        const short8_t af1 = *(const short8_t*)(Lb + a1off + col);
#pragma unroll
        for (int nt = 0; nt < 8; ++nt) {
            const short8_t bf =
                *(const short8_t*)(ss_t + (size_t)(nt * 16 + m) * NN + col);
            acc[0][nt] = __builtin_amdgcn_mfma_f32_16x16x32_bf16(af0, bf,
                                                                 acc[0][nt], 0, 0, 0);
            acc[1][nt] = __builtin_amdgcn_mfma_f32_16x16x32_bf16(af1, bf,
                                                                 acc[1][nt], 0, 0, 0);
        }
    }

    // C/D layout: col = lane&15, row = (lane>>4)*4 + reg  [measured m89/m91]
#pragma unroll
    for (int f = 0; f < 2; ++f) {
#pragma unroll
        for (int nt = 0; nt < 8; ++nt) {
            const int n = nt * 16 + m;
#pragma unroll
            for (int r = 0; r < 4; ++r) {
                const int ro = i0 + wave * 32 + f * 16 + 4 * b + r;
                float v = acc[f][nt][r];
                if (ATOMIC) {
                    if (ks == 0) v += bf2f(ss_t[(size_t)n * NN + ro]);
                    atomicAdd(outp + (size_t)ro * FF + n, s[ro] * v);
                } else {
                    outp[(size_t)ks * NN * FF + (size_t)ro * FF + n] = v;
                }
            }
        }
    }
}

// Reduce KSPLIT partials + identity term + row scaling -> out (f32).
__global__ __launch_bounds__(256) void reduce_kernel(
    const float* __restrict__ part, const unsigned short* __restrict__ ss_t,
    const float* __restrict__ s, float* __restrict__ out)
{
    const int idx = blockIdx.x * 256 + threadIdx.x;   // 0 .. NN*FF-1
    const int gi = idx >> 7;          // row i
    const int cc = idx & 127;         // col n
    float v = 0.f;
#pragma unroll
    for (int k = 0; k < KSPLIT; ++k) v += part[(size_t)k * NN * FF + idx];
    v += bf2f(ss_t[(size_t)cc * NN + gi]);            // + I * SS
    out[idx] = s[gi] * v;
}

extern "C" void kernel_launch(void* const* d_in, const int* in_sizes, int n_in,
                              void* d_out, int out_size, void* d_ws, size_t ws_size,
                              hipStream_t stream) {
    const float* x     = (const float*)d_in[0];
    const float* adj   = (const float*)d_in[1];
    const float* w     = (const float*)d_in[3];
    const float* learn = (const float*)d_in[4];
    float* out = (float*)d_out;

    // ws layout: degree | s | ss_t | Lb | (part)
    float* degree = (float*)d_ws;
    float* s      = degree + NN;
    unsigned short* ss_t = (unsigned short*)(s + NN);
    unsigned short* Lb   = ss_t + (size_t)FF * NN;
    float* part          = (float*)(Lb + (size_t)NN * NN);

    const size_t need_base = 2 * NN * 4 + (size_t)FF * NN * 2
                           + (size_t)NN * NN * 2;
    const size_t need_part = need_base + (size_t)KSPLIT * NN * FF * 4; // ~162 MB

    hipMemsetAsync(degree, 0, NN * sizeof(float), stream);
    fuse_combine_kernel<<<NN * 2, 256, 0, stream>>>(adj, learn, Lb, degree);
    s_kernel<<<NN / 256, 256, 0, stream>>>(degree, s);
    support_kernel<<<NN / 32, 256, 0, stream>>>(x, w, s, ss_t);

    if (ws_size >= need_part) {
        spmm_bf16_kernel<false><<<dim3(NN / 128, KSPLIT), 256, 0, stream>>>(
            Lb, ss_t, s, part);
        reduce_kernel<<<NN * FF / 256, 256, 0, stream>>>(part, ss_t, s, out);
    } else {
        hipMemsetAsync(d_out, 0, (size_t)NN * FF * sizeof(float), stream);
        spmm_bf16_kernel<true><<<dim3(NN / 128, KSPLIT), 256, 0, stream>>>(
            Lb, ss_t, s, out);
    }
}